// Round 15
// baseline (713.356 us; speedup 1.0000x reference)
//
#include <hip/hip_runtime.h>
#include <math.h>

#define HH 96
#define WW 128
#define DD 64
#define BB 8
#define KK 7
#define CC 32
#define HWSZ (HH*WW)
#define EPSF 1e-8f
#define NCH 16               // channel-pair chunks (2 f16 ch per u32)
#define NDT 16               // depths per thread
#define PXT 256              // pixels per block tile
#define ROWB 512             // LDS row stride bytes = 128 px * 4B (linear for gload_lds)
#define BIAS 528             // front pad bytes (zeroed; covers iyb=-1 reads)
#define BUFB (BIAS + HH*ROWB + 528)    // 50208 bytes
#define BUFW (BUFB/4)                  // 12552 u32

typedef _Float16 h2 __attribute__((ext_vector_type(2)));

static __device__ __forceinline__ float bf_lo(unsigned u){ return __uint_as_float(u << 16); }
static __device__ __forceinline__ float bf_hi(unsigned u){ return __uint_as_float(u & 0xffff0000u); }
static __device__ __forceinline__ unsigned f2bf(float f){
    unsigned u = __float_as_uint(f);
    return (u + 0x7fffu + ((u >> 16) & 1u)) >> 16;   // RNE
}
static __device__ __forceinline__ unsigned packh2(float a, float b){
    unsigned short ha = __builtin_bit_cast(unsigned short, (_Float16)a);
    unsigned short hb = __builtin_bit_cast(unsigned short, (_Float16)b);
    return ((unsigned)hb << 16) | ha;
}
static __device__ __forceinline__ float dot2h(unsigned a, unsigned b){
#if __has_builtin(__builtin_amdgcn_fdot2)
    return __builtin_amdgcn_fdot2(__builtin_bit_cast(h2, a), __builtin_bit_cast(h2, b), 0.f, false);
#else
    h2 ha = __builtin_bit_cast(h2, a), hb = __builtin_bit_cast(h2, b);
    return (float)ha.x * (float)hb.x + (float)ha.y * (float)hb.y;
#endif
}
static __device__ __forceinline__ void g2lds16(const unsigned* g, unsigned* l){
    __builtin_amdgcn_global_load_lds(
        (const __attribute__((address_space(1))) void*)g,
        (__attribute__((address_space(3))) void*)l, 16, 0, 0);
}

// ---- pack src: (B*K, C, HW) f32 -> (B*K, 16, HW) u32 of 2 f16 ch ----
__global__ __launch_bounds__(256) void pack_src2(const float* __restrict__ in,
                                                 unsigned* __restrict__ outP)
{
    int gid = blockIdx.x * 256 + threadIdx.x;
    int px  = gid % HWSZ;
    int rest = gid / HWSZ;
    int cc  = rest % NCH;
    int v   = rest / NCH;
    if (v >= BB*KK) return;
    const float* ip = in + (size_t)(v*CC + 2*cc)*HWSZ + px;
    outP[(size_t)(v*NCH + cc)*HWSZ + px] = packh2(ip[0], ip[HWSZ]);
}

// ---- pack cur: (B, C, HW) f32 -> (B, 16, HW) u32 of 2 f16 ch ----
__global__ __launch_bounds__(256) void pack_cur2(const float* __restrict__ in,
                                                 unsigned* __restrict__ outP)
{
    int gid = blockIdx.x * 256 + threadIdx.x;
    int px  = gid % HWSZ;
    int rest = gid / HWSZ;
    int cc  = rest % NCH;
    int b   = rest / NCH;
    if (b >= BB) return;
    const float* ip = in + (size_t)(b*CC + 2*cc)*HWSZ + px;
    outP[(size_t)(b*NCH + cc)*HWSZ + px] = packh2(ip[0], ip[HWSZ]);
}

// ---- main: round-9 structure + per-(block,k) row-band staging ----
__global__ __launch_bounds__(512, 4) void cv_lds(
    const unsigned* __restrict__ curPh,  // (B,16,HW) u32 (2 f16)
    const unsigned* __restrict__ srcC,   // (B,K,16,HW) u32 (2 f16)
    const float* __restrict__ Emat,
    const float* __restrict__ Kmat,
    const float* __restrict__ invK,
    const float* __restrict__ mnp,
    const float* __restrict__ mxp,
    float* __restrict__ out)
{
    __shared__ unsigned sbuf[BUFW];
    __shared__ float sM[KK][12];
    __shared__ int sMm[16];              // 8 waves x {min,max} of iyb

    int blk   = blockIdx.x;
    int b     = blk & 7;          // XCD-pinned batch
    int r     = blk >> 3;
    int dhalf = r & 1;
    int tile  = r >> 1;
    int tid   = threadIdx.x;
    int wbase = tid & ~63;        // wave-uniform

    // Zero the ENTIRE buffer once (NaN-proof: any byte not overwritten by a
    // band stage reads as 0.0; weight-0 taps then contribute exactly 0).
    for (int i = tid; i < BUFW; i += 512) sbuf[i] = 0;

    if (tid < KK) {
        int k = tid;
        const float* Km = Kmat + (size_t)(b*KK + k)*16;
        const float* Em = Emat + (size_t)(b*KK + k)*16;
        float P[3][4];
        #pragma unroll
        for (int i = 0; i < 3; ++i)
            #pragma unroll
            for (int jj = 0; jj < 4; ++jj) {
                float s = 0.f;
                #pragma unroll
                for (int l = 0; l < 4; ++l) s = fmaf(Km[i*4+l], Em[l*4+jj], s);
                P[i][jj] = s;
            }
        const float* iK = invK + (size_t)b*16;
        #pragma unroll
        for (int i = 0; i < 3; ++i) {
            #pragma unroll
            for (int jj = 0; jj < 3; ++jj) {
                float s = 0.f;
                #pragma unroll
                for (int l = 0; l < 3; ++l) s = fmaf(P[i][l], iK[l*4+jj], s);
                sM[k][i*4+jj] = s;
            }
            sM[k][i*4+3] = P[i][3];
        }
    }
    __syncthreads();

    int p     = tile*PXT + (tid & 255);
    int dg    = tid >> 8;                 // 0 or 1
    int dbase = dhalf*32 + dg*NDT;
    float fx = (float)(p & (WW-1)) + 0.5f;
    float fy = (float)(p >> 7) + 0.5f;

    float mnb = mnp[b];
    float lmn = logf(mnb);
    float lr  = logf(mxp[b] / mnb);
    float d0   = expf(fmaf(lr, (float)dbase * (1.f/63.f), lmn));
    float rdep = expf(lr * (1.f/63.f));   // geometric depth step

    float acc[NDT];
    #pragma unroll
    for (int d = 0; d < NDT; ++d) acc[d] = 0.f;

    unsigned offsP[NDT/2];    // packed dword-offsets, 2 per u32
    unsigned wA[NDT], wB[NDT];
    const char* bp = (const char*)sbuf;

    for (int k = 0; k < KK; ++k) {
        float q0 = fmaf(sM[k][0], fx, fmaf(sM[k][1], fy, sM[k][2]));
        float q1 = fmaf(sM[k][4], fx, fmaf(sM[k][5], fy, sM[k][6]));
        float q2 = fmaf(sM[k][8], fx, fmaf(sM[k][9], fy, sM[k][10]));
        float m3 = sM[k][3], m7 = sM[k][7], m11 = sM[k][11];

        int iyMin = 95, iyMax = -1;
        float depth = d0;
        #pragma unroll
        for (int d = 0; d < NDT; ++d) {
            float cam0 = fmaf(depth, q0, m3);
            float cam1 = fmaf(depth, q1, m7);
            float zraw = fmaf(depth, q2, m11);
            depth *= rdep;
            float z     = zraw + EPSF;
            float scale = (fabsf(zraw) > EPSF) ? (1.f / z) : 1.f;
            float x = cam0 * scale - 0.5f;
            float y = cam1 * scale - 0.5f;
            float x0f = floorf(x), y0f = floorf(y);
            float wx1 = x - x0f,  wy1 = y - y0f;
            float wx0 = 1.f - wx1, wy0 = 1.f - wy1;
            bool vx0 = (x0f >=  0.f) && (x0f <= 127.f);
            bool vx1 = (x0f >= -1.f) && (x0f <= 126.f);
            bool vy0 = (y0f >=  0.f) && (y0f <=  95.f);
            bool vy1 = (y0f >= -1.f) && (y0f <=  94.f);
            float zm = (z > 0.f) ? 1.f : 0.f;
            float w00 = (vx0 && vy0) ? wx0*wy0*zm : 0.f;
            float w01 = (vx1 && vy0) ? wx1*wy0*zm : 0.f;
            float w10 = (vx0 && vy1) ? wx0*wy1*zm : 0.f;
            float w11 = (vx1 && vy1) ? wx1*wy1*zm : 0.f;
            int ixb = (int)fminf(fmaxf(x0f, -1.f), 127.f);
            int iyb = (int)fminf(fmaxf(y0f, -1.f),  95.f);
            iyMin = min(iyMin, iyb);
            iyMax = max(iyMax, iyb);
            unsigned doff = (unsigned)((BIAS/4) + iyb*(ROWB/4) + ixb);
            if ((d & 1) == 0) offsP[d>>1] = doff;
            else              offsP[d>>1] |= (doff << 16);
            wA[d] = (f2bf(w01) << 16) | f2bf(w00);
            wB[d] = (f2bf(w11) << 16) | f2bf(w10);
        }

        // wave-level min/max of iyb, lane0 publishes per-wave result
        #pragma unroll
        for (int s = 1; s < 64; s <<= 1) {
            iyMin = min(iyMin, __shfl_xor(iyMin, s));
            iyMax = max(iyMax, __shfl_xor(iyMax, s));
        }
        if ((tid & 63) == 0) {
            sMm[(tid >> 6)*2    ] = iyMin;
            sMm[(tid >> 6)*2 + 1] = iyMax;
        }

        const unsigned* kbase = srcC + (size_t)(b*KK + k)*NCH*HWSZ;
        int r0 = 0, N4 = HH*32;

        for (int cc = 0; cc < NCH; ++cc) {
            unsigned cp = curPh[(size_t)(b*NCH + cc)*HWSZ + p];   // issued pre-barrier
            __syncthreads();   // prior gathers done; (cc==0) sMm visible
            if (cc == 0) {
                int mn = 95, mx = -1;
                #pragma unroll
                for (int wv = 0; wv < 8; ++wv) {
                    mn = min(mn, sMm[2*wv]);
                    mx = max(mx, sMm[2*wv+1]);
                }
                // Band must cover the full read-set of clamped taps:
                //  - ixb=-1 taps read the LAST dword of row iyb-1  -> rr0 = mn-1
                //  - t01/t11 at ixb=127 read the FIRST dword of row iyb+2 -> rr1 = mx+2
                // (reads beyond rows [0,95] land in the zeroed front/back pads)
                int rr0 = max(0, mn - 1);
                int rr1 = min(HH-1, mx + 2);
                int cnt = rr1 - rr0 + 1;
                if (cnt & 1) { if (rr1 < HH-1) rr1++; else rr0--; }  // even rows -> full waves
                r0 = max(0, rr0);
                N4 = (rr1 - r0 + 1) << 5;          // uint4 count (32 per row)
            }
            // stage only rows [r0 .. rr1]: N4 x 16B, linear, full-wave chunks
            {
                const unsigned* gs = kbase + (size_t)cc*HWSZ + r0*(ROWB/4);
                unsigned* lb = sbuf + (BIAS/4) + r0*(ROWB/4);
                #pragma unroll
                for (int c = 0; c < 6; ++c) {
                    if (c*512 + wbase < N4)        // wave-uniform predicate
                        g2lds16(gs + (size_t)(c*512 + tid)*4,
                                lb + (size_t)(c*512 + wbase)*4);
                }
            }
            __syncthreads();   // drains vmcnt -> band ready

            #pragma unroll
            for (int d = 0; d < NDT; ++d) {
                unsigned doff = (offsP[d>>1] >> ((d & 1)*16)) & 0xffffu;
                const char* tp = bp + doff*4;
                unsigned t00 = *reinterpret_cast<const unsigned*>(tp);
                unsigned t01 = *reinterpret_cast<const unsigned*>(tp + 4);
                unsigned t10 = *reinterpret_cast<const unsigned*>(tp + ROWB);
                unsigned t11 = *reinterpret_cast<const unsigned*>(tp + ROWB + 4);
                float td00 = dot2h(t00, cp);
                float td01 = dot2h(t01, cp);
                float td10 = dot2h(t10, cp);
                float td11 = dot2h(t11, cp);
                unsigned wa = wA[d], wb = wB[d];
                float s = acc[d];
                s = fmaf(bf_lo(wa), td00, s);
                s = fmaf(bf_hi(wa), td01, s);
                s = fmaf(bf_lo(wb), td10, s);
                s = fmaf(bf_hi(wb), td11, s);
                acc[d] = s;
            }
        }
    }

    #pragma unroll
    for (int d = 0; d < NDT; ++d)
        out[(size_t)(b*DD + dbase + d)*HWSZ + p] = acc[d];
}

// ---------- fallback (ws too small): round-1 style, known correct ----------
__global__ __launch_bounds__(256) void cv_fallback(
    const float* __restrict__ cur, const float* __restrict__ src,
    const float* __restrict__ Emat, const float* __restrict__ Kmat,
    const float* __restrict__ invK, const float* __restrict__ mnp,
    const float* __restrict__ mxp, float* __restrict__ out)
{
    int blk  = blockIdx.x;
    int tile = blk % (HWSZ/256);
    int bd   = blk / (HWSZ/256);
    int d    = bd % DD;
    int b    = bd / DD;
    __shared__ float sM[KK][12];
    __shared__ float sDepth;
    if (threadIdx.x < KK) {
        int k = threadIdx.x;
        const float* Km = Kmat + (size_t)(b*KK + k)*16;
        const float* Em = Emat + (size_t)(b*KK + k)*16;
        float P[3][4];
        #pragma unroll
        for (int i = 0; i < 3; ++i)
            #pragma unroll
            for (int jj = 0; jj < 4; ++jj) {
                float s = 0.f;
                #pragma unroll
                for (int l = 0; l < 4; ++l) s = fmaf(Km[i*4+l], Em[l*4+jj], s);
                P[i][jj] = s;
            }
        const float* iK = invK + (size_t)b*16;
        #pragma unroll
        for (int i = 0; i < 3; ++i) {
            #pragma unroll
            for (int jj = 0; jj < 3; ++jj) {
                float s = 0.f;
                #pragma unroll
                for (int l = 0; l < 3; ++l) s = fmaf(P[i][l], iK[l*4+jj], s);
                sM[k][i*4+jj] = s;
            }
            sM[k][i*4+3] = P[i][3];
        }
    }
    if (threadIdx.x == KK) {
        float mnb = mnp[b], mxb = mxp[b];
        sDepth = expf(logf(mnb) + logf(mxb/mnb) * ((float)d * (1.f/63.f)));
    }
    __syncthreads();
    int p  = tile*256 + threadIdx.x;
    float fx = (float)(p & (WW-1)) + 0.5f;
    float fy = (float)(p >> 7) + 0.5f;
    float depth = sDepth;
    float curv[CC];
    const float* curp = cur + (size_t)b*CC*HWSZ + p;
    #pragma unroll
    for (int c = 0; c < CC; ++c) curv[c] = curp[(size_t)c*HWSZ];
    float acc = 0.f;
    for (int k = 0; k < KK; ++k) {
        float q0 = fmaf(sM[k][0], fx, fmaf(sM[k][1], fy, sM[k][2]));
        float q1 = fmaf(sM[k][4], fx, fmaf(sM[k][5], fy, sM[k][6]));
        float q2 = fmaf(sM[k][8], fx, fmaf(sM[k][9], fy, sM[k][10]));
        float cam0 = fmaf(depth, q0, sM[k][3]);
        float cam1 = fmaf(depth, q1, sM[k][7]);
        float zraw = fmaf(depth, q2, sM[k][11]);
        float z     = zraw + EPSF;
        float scale = (fabsf(zraw) > EPSF) ? (1.f / z) : 1.f;
        float x = cam0 * scale - 0.5f;
        float y = cam1 * scale - 0.5f;
        float x0f = floorf(x), y0f = floorf(y);
        float wx1 = x - x0f,  wy1 = y - y0f;
        float wx0 = 1.f - wx1, wy0 = 1.f - wy1;
        bool vx0 = (x0f >= 0.f)   && (x0f <= 127.f);
        bool vx1 = (x0f >= -1.f)  && (x0f <= 126.f);
        bool vy0 = (y0f >= 0.f)   && (y0f <= 95.f);
        bool vy1 = (y0f >= -1.f)  && (y0f <= 94.f);
        float zm = (z > 0.f) ? 1.f : 0.f;
        float w00 = (vx0 && vy0) ? wx0*wy0*zm : 0.f;
        float w01 = (vx1 && vy0) ? wx1*wy0*zm : 0.f;
        float w10 = (vx0 && vy1) ? wx0*wy1*zm : 0.f;
        float w11 = (vx1 && vy1) ? wx1*wy1*zm : 0.f;
        int ix0 = (int)fminf(fmaxf(x0f,       0.f), 127.f);
        int ix1 = (int)fminf(fmaxf(x0f + 1.f, 0.f), 127.f);
        int iy0 = (int)fminf(fmaxf(y0f,       0.f), 95.f);
        int iy1 = (int)fminf(fmaxf(y0f + 1.f, 0.f), 95.f);
        const float* sb = src + (size_t)(b*KK + k)*CC*HWSZ;
        int o0 = iy0*WW+ix0, o1 = iy0*WW+ix1, o2 = iy1*WW+ix0, o3 = iy1*WW+ix1;
        float a0=0.f,a1=0.f,a2=0.f,a3=0.f;
        #pragma unroll 8
        for (int c = 0; c < CC; ++c) {
            const float* sc = sb + (size_t)c*HWSZ;
            a0 = fmaf(curv[c], sc[o0], a0);
            a1 = fmaf(curv[c], sc[o1], a1);
            a2 = fmaf(curv[c], sc[o2], a2);
            a3 = fmaf(curv[c], sc[o3], a3);
        }
        acc += w00*a0 + w01*a1 + w10*a2 + w11*a3;
    }
    out[(size_t)(b*DD + d)*HWSZ + p] = acc;
}

extern "C" void kernel_launch(void* const* d_in, const int* in_sizes, int n_in,
                              void* d_out, int out_size, void* d_ws, size_t ws_size,
                              hipStream_t stream) {
    const float* cur   = (const float*)d_in[0];
    const float* srcf  = (const float*)d_in[1];
    const float* Emat  = (const float*)d_in[2];
    const float* Kmat  = (const float*)d_in[3];
    const float* invK  = (const float*)d_in[4];
    const float* mn    = (const float*)d_in[5];
    const float* mx    = (const float*)d_in[6];
    float* out = (float*)d_out;

    const size_t srcC_bytes = (size_t)BB*KK*NCH*HWSZ*4;   // 44 MB
    const size_t curP_bytes = (size_t)BB*NCH*HWSZ*4;      // 6.3 MB

    if (ws_size >= srcC_bytes + curP_bytes) {
        unsigned* srcC = (unsigned*)d_ws;
        unsigned* curP = (unsigned*)((char*)d_ws + srcC_bytes);
        int nsrc = BB*KK*NCH*HWSZ;
        int ncur = BB*NCH*HWSZ;
        pack_src2<<<dim3((nsrc + 255)/256), dim3(256), 0, stream>>>(srcf, srcC);
        pack_cur2<<<dim3((ncur + 255)/256), dim3(256), 0, stream>>>(cur, curP);
        cv_lds<<<dim3(BB*(HWSZ/PXT)*2), dim3(512), 0, stream>>>(curP, srcC, Emat, Kmat, invK, mn, mx, out);
    } else {
        cv_fallback<<<dim3(BB*DD*(HWSZ/256)), dim3(256), 0, stream>>>(cur, srcf, Emat, Kmat, invK, mn, mx, out);
    }
}

// Round 16
// 504.939 us; speedup vs baseline: 1.4128x; 1.4128x over previous
//
#include <hip/hip_runtime.h>
#include <math.h>

#define HH 96
#define WW 128
#define DD 64
#define BB 8
#define KK 7
#define CC 32
#define HWSZ (HH*WW)
#define EPSF 1e-8f
#define NCH4 8               // 4-channel chunks (4 f16 per 8B pixel)
#define NDT 8                // depths per thread
#define PXT 128              // pixels per block tile
#define NTHR 1024            // 128 px x 8 depth-groups
#define ROWB 1024            // LDS row stride bytes = 128 px * 8B
#define BIAS 1040            // front pad (zeroed; covers iyb=-1, ixb=-1 reads)
#define BACK 1040            // back pad (zeroed; covers iyb=95 +ROWB reads)
#define BUFB (BIAS + HH*ROWB + BACK)   // 100384 bytes
#define BUFW (BUFB/4)                  // 25096 u32

typedef _Float16 h2 __attribute__((ext_vector_type(2)));

static __device__ __forceinline__ unsigned packh2(float a, float b){
    unsigned short ha = __builtin_bit_cast(unsigned short, (_Float16)a);
    unsigned short hb = __builtin_bit_cast(unsigned short, (_Float16)b);
    return ((unsigned)hb << 16) | ha;
}
static __device__ __forceinline__ float dot2a(unsigned a, unsigned b, float c){
#if __has_builtin(__builtin_amdgcn_fdot2)
    return __builtin_amdgcn_fdot2(__builtin_bit_cast(h2, a), __builtin_bit_cast(h2, b), c, false);
#else
    h2 ha = __builtin_bit_cast(h2, a), hb = __builtin_bit_cast(h2, b);
    return c + (float)ha.x * (float)hb.x + (float)ha.y * (float)hb.y;
#endif
}
static __device__ __forceinline__ void g2lds16(const unsigned* g, unsigned* l){
    __builtin_amdgcn_global_load_lds(
        (const __attribute__((address_space(1))) void*)g,
        (__attribute__((address_space(3))) void*)l, 16, 0, 0);
}

// ---- pack src: (B*K, C, HW) f32 -> (B*K, 8, HW) uint2 of 4 f16 ch ----
__global__ __launch_bounds__(256) void pack_src4(const float* __restrict__ in,
                                                 uint2* __restrict__ outP)
{
    int gid = blockIdx.x * 256 + threadIdx.x;
    int px  = gid % HWSZ;
    int rest = gid / HWSZ;
    int cc  = rest % NCH4;
    int v   = rest / NCH4;
    if (v >= BB*KK) return;
    const float* ip = in + (size_t)(v*CC + 4*cc)*HWSZ + px;
    uint2 o;
    o.x = packh2(ip[0],        ip[HWSZ]);
    o.y = packh2(ip[2*HWSZ],   ip[3*HWSZ]);
    outP[(size_t)(v*NCH4 + cc)*HWSZ + px] = o;
}

// ---- pack cur: (B, C, HW) f32 -> (B, 8, HW) uint2 of 4 f16 ch ----
__global__ __launch_bounds__(256) void pack_cur4(const float* __restrict__ in,
                                                 uint2* __restrict__ outP)
{
    int gid = blockIdx.x * 256 + threadIdx.x;
    int px  = gid % HWSZ;
    int rest = gid / HWSZ;
    int cc  = rest % NCH4;
    int b   = rest / NCH4;
    if (b >= BB) return;
    const float* ip = in + (size_t)(b*CC + 4*cc)*HWSZ + px;
    uint2 o;
    o.x = packh2(ip[0],        ip[HWSZ]);
    o.y = packh2(ip[2*HWSZ],   ip[3*HWSZ]);
    outP[(size_t)(b*NCH4 + cc)*HWSZ + px] = o;
}

// ---- main: 4ch/8B pixels, b64 taps, 1024 thr (all 64 depths), 1 block/CU ----
__global__ __launch_bounds__(NTHR, 4) void cv_lds4(
    const uint2* __restrict__ curP4,     // (B,8,HW) uint2 (4 f16)
    const unsigned* __restrict__ srcC,   // (B,K,8,HW) uint2 viewed as u32
    const float* __restrict__ Emat,
    const float* __restrict__ Kmat,
    const float* __restrict__ invK,
    const float* __restrict__ mnp,
    const float* __restrict__ mxp,
    float* __restrict__ out)
{
    __shared__ unsigned sbuf[BUFW];
    __shared__ float sM[KK][12];

    int blk   = blockIdx.x;
    int b     = blk & 7;          // XCD-pinned batch
    int tile  = blk >> 3;         // 0..95
    int tid   = threadIdx.x;
    int wbase = tid & ~63;        // wave-uniform

    // zero front/back pads once (only bytes outside staged rows ever read,
    // always with weight 0; 0 x finite = 0)
    if (tid < BIAS/4)  sbuf[tid] = 0;
    if (tid < BACK/4)  sbuf[BIAS/4 + HH*(ROWB/4) + tid] = 0;

    if (tid < KK) {
        int k = tid;
        const float* Km = Kmat + (size_t)(b*KK + k)*16;
        const float* Em = Emat + (size_t)(b*KK + k)*16;
        float P[3][4];
        #pragma unroll
        for (int i = 0; i < 3; ++i)
            #pragma unroll
            for (int jj = 0; jj < 4; ++jj) {
                float s = 0.f;
                #pragma unroll
                for (int l = 0; l < 4; ++l) s = fmaf(Km[i*4+l], Em[l*4+jj], s);
                P[i][jj] = s;
            }
        const float* iK = invK + (size_t)b*16;
        #pragma unroll
        for (int i = 0; i < 3; ++i) {
            #pragma unroll
            for (int jj = 0; jj < 3; ++jj) {
                float s = 0.f;
                #pragma unroll
                for (int l = 0; l < 3; ++l) s = fmaf(P[i][l], iK[l*4+jj], s);
                sM[k][i*4+jj] = s;
            }
            sM[k][i*4+3] = P[i][3];
        }
    }
    __syncthreads();

    int p     = tile*PXT + (tid & 127);
    int dg    = tid >> 7;                 // 0..7
    int dbase = dg * NDT;
    float fx = (float)(p & (WW-1)) + 0.5f;
    float fy = (float)(p >> 7) + 0.5f;

    float mnb = mnp[b];
    float lmn = logf(mnb);
    float lr  = logf(mxp[b] / mnb);
    float d0   = expf(fmaf(lr, (float)dbase * (1.f/63.f), lmn));
    float rdep = expf(lr * (1.f/63.f));   // geometric depth step

    float acc[NDT];
    #pragma unroll
    for (int d = 0; d < NDT; ++d) acc[d] = 0.f;

    unsigned vadr[NDT];                               // byte offsets in sbuf
    float w00a[NDT], w01a[NDT], w10a[NDT], w11a[NDT]; // f32 weights
    const char* bp = (const char*)sbuf;

    for (int k = 0; k < KK; ++k) {
        float q0 = fmaf(sM[k][0], fx, fmaf(sM[k][1], fy, sM[k][2]));
        float q1 = fmaf(sM[k][4], fx, fmaf(sM[k][5], fy, sM[k][6]));
        float q2 = fmaf(sM[k][8], fx, fmaf(sM[k][9], fy, sM[k][10]));
        float m3 = sM[k][3], m7 = sM[k][7], m11 = sM[k][11];

        float depth = d0;
        #pragma unroll
        for (int d = 0; d < NDT; ++d) {
            float cam0 = fmaf(depth, q0, m3);
            float cam1 = fmaf(depth, q1, m7);
            float zraw = fmaf(depth, q2, m11);
            depth *= rdep;
            float z     = zraw + EPSF;
            float scale = (fabsf(zraw) > EPSF) ? (1.f / z) : 1.f;
            float x = cam0 * scale - 0.5f;
            float y = cam1 * scale - 0.5f;
            float x0f = floorf(x), y0f = floorf(y);
            float wx1 = x - x0f,  wy1 = y - y0f;
            float wx0 = 1.f - wx1, wy0 = 1.f - wy1;
            bool vx0 = (x0f >=  0.f) && (x0f <= 127.f);
            bool vx1 = (x0f >= -1.f) && (x0f <= 126.f);
            bool vy0 = (y0f >=  0.f) && (y0f <=  95.f);
            bool vy1 = (y0f >= -1.f) && (y0f <=  94.f);
            float zm = (z > 0.f) ? 1.f : 0.f;
            w00a[d] = (vx0 && vy0) ? wx0*wy0*zm : 0.f;
            w01a[d] = (vx1 && vy0) ? wx1*wy0*zm : 0.f;
            w10a[d] = (vx0 && vy1) ? wx0*wy1*zm : 0.f;
            w11a[d] = (vx1 && vy1) ? wx1*wy1*zm : 0.f;
            int ixb = (int)fminf(fmaxf(x0f, -1.f), 127.f);
            int iyb = (int)fminf(fmaxf(y0f, -1.f),  95.f);
            vadr[d] = (unsigned)(BIAS + iyb*ROWB + ixb*8);
        }

        const unsigned* kbase = srcC + (size_t)(b*KK + k)*NCH4*HWSZ*2;

        for (int cc = 0; cc < NCH4; ++cc) {
            uint2 cp = curP4[(size_t)(b*NCH4 + cc)*HWSZ + p];   // issued pre-barrier
            __syncthreads();   // prior gathers done before overwrite
            // async stage 96KB slice: 6 x global_load_lds dwordx4 per thread
            {
                const unsigned* gs = kbase + (size_t)cc*HWSZ*2;
                #pragma unroll
                for (int i = 0; i < 6; ++i) {
                    const unsigned* g = gs + (size_t)(i*NTHR + tid)*4;
                    unsigned* l = sbuf + (BIAS/4) + (size_t)(i*NTHR + wbase)*4;
                    g2lds16(g, l);
                }
            }
            __syncthreads();   // drains vmcnt -> LDS ready

            #pragma unroll
            for (int d = 0; d < NDT; ++d) {
                const char* tp = bp + vadr[d];
                uint2 t00 = *reinterpret_cast<const uint2*>(tp);
                uint2 t01 = *reinterpret_cast<const uint2*>(tp + 8);
                uint2 t10 = *reinterpret_cast<const uint2*>(tp + ROWB);
                uint2 t11 = *reinterpret_cast<const uint2*>(tp + ROWB + 8);
                float d00 = dot2a(t00.y, cp.y, dot2a(t00.x, cp.x, 0.f));
                float d01 = dot2a(t01.y, cp.y, dot2a(t01.x, cp.x, 0.f));
                float d10 = dot2a(t10.y, cp.y, dot2a(t10.x, cp.x, 0.f));
                float d11 = dot2a(t11.y, cp.y, dot2a(t11.x, cp.x, 0.f));
                float s = acc[d];
                s = fmaf(w00a[d], d00, s);
                s = fmaf(w01a[d], d01, s);
                s = fmaf(w10a[d], d10, s);
                s = fmaf(w11a[d], d11, s);
                acc[d] = s;
            }
        }
    }

    #pragma unroll
    for (int d = 0; d < NDT; ++d)
        out[(size_t)(b*DD + dbase + d)*HWSZ + p] = acc[d];
}

// ---------- fallback (ws too small): round-1 style, known correct ----------
__global__ __launch_bounds__(256) void cv_fallback(
    const float* __restrict__ cur, const float* __restrict__ src,
    const float* __restrict__ Emat, const float* __restrict__ Kmat,
    const float* __restrict__ invK, const float* __restrict__ mnp,
    const float* __restrict__ mxp, float* __restrict__ out)
{
    int blk  = blockIdx.x;
    int tile = blk % (HWSZ/256);
    int bd   = blk / (HWSZ/256);
    int d    = bd % DD;
    int b    = bd / DD;
    __shared__ float sM[KK][12];
    __shared__ float sDepth;
    if (threadIdx.x < KK) {
        int k = threadIdx.x;
        const float* Km = Kmat + (size_t)(b*KK + k)*16;
        const float* Em = Emat + (size_t)(b*KK + k)*16;
        float P[3][4];
        #pragma unroll
        for (int i = 0; i < 3; ++i)
            #pragma unroll
            for (int jj = 0; jj < 4; ++jj) {
                float s = 0.f;
                #pragma unroll
                for (int l = 0; l < 4; ++l) s = fmaf(Km[i*4+l], Em[l*4+jj], s);
                P[i][jj] = s;
            }
        const float* iK = invK + (size_t)b*16;
        #pragma unroll
        for (int i = 0; i < 3; ++i) {
            #pragma unroll
            for (int jj = 0; jj < 3; ++jj) {
                float s = 0.f;
                #pragma unroll
                for (int l = 0; l < 3; ++l) s = fmaf(P[i][l], iK[l*4+jj], s);
                sM[k][i*4+jj] = s;
            }
            sM[k][i*4+3] = P[i][3];
        }
    }
    if (threadIdx.x == KK) {
        float mnb = mnp[b], mxb = mxp[b];
        sDepth = expf(logf(mnb) + logf(mxb/mnb) * ((float)d * (1.f/63.f)));
    }
    __syncthreads();
    int p  = tile*256 + threadIdx.x;
    float fx = (float)(p & (WW-1)) + 0.5f;
    float fy = (float)(p >> 7) + 0.5f;
    float depth = sDepth;
    float curv[CC];
    const float* curp = cur + (size_t)b*CC*HWSZ + p;
    #pragma unroll
    for (int c = 0; c < CC; ++c) curv[c] = curp[(size_t)c*HWSZ];
    float acc = 0.f;
    for (int k = 0; k < KK; ++k) {
        float q0 = fmaf(sM[k][0], fx, fmaf(sM[k][1], fy, sM[k][2]));
        float q1 = fmaf(sM[k][4], fx, fmaf(sM[k][5], fy, sM[k][6]));
        float q2 = fmaf(sM[k][8], fx, fmaf(sM[k][9], fy, sM[k][10]));
        float cam0 = fmaf(depth, q0, sM[k][3]);
        float cam1 = fmaf(depth, q1, sM[k][7]);
        float zraw = fmaf(depth, q2, sM[k][11]);
        float z     = zraw + EPSF;
        float scale = (fabsf(zraw) > EPSF) ? (1.f / z) : 1.f;
        float x = cam0 * scale - 0.5f;
        float y = cam1 * scale - 0.5f;
        float x0f = floorf(x), y0f = floorf(y);
        float wx1 = x - x0f,  wy1 = y - y0f;
        float wx0 = 1.f - wx1, wy0 = 1.f - wy1;
        bool vx0 = (x0f >= 0.f)   && (x0f <= 127.f);
        bool vx1 = (x0f >= -1.f)  && (x0f <= 126.f);
        bool vy0 = (y0f >= 0.f)   && (y0f <= 95.f);
        bool vy1 = (y0f >= -1.f)  && (y0f <= 94.f);
        float zm = (z > 0.f) ? 1.f : 0.f;
        float w00 = (vx0 && vy0) ? wx0*wy0*zm : 0.f;
        float w01 = (vx1 && vy0) ? wx1*wy0*zm : 0.f;
        float w10 = (vx0 && vy1) ? wx0*wy1*zm : 0.f;
        float w11 = (vx1 && vy1) ? wx1*wy1*zm : 0.f;
        int ix0 = (int)fminf(fmaxf(x0f,       0.f), 127.f);
        int ix1 = (int)fminf(fmaxf(x0f + 1.f, 0.f), 127.f);
        int iy0 = (int)fminf(fmaxf(y0f,       0.f), 95.f);
        int iy1 = (int)fminf(fmaxf(y0f + 1.f, 0.f), 95.f);
        const float* sb = src + (size_t)(b*KK + k)*CC*HWSZ;
        int o0 = iy0*WW+ix0, o1 = iy0*WW+ix1, o2 = iy1*WW+ix0, o3 = iy1*WW+ix1;
        float a0=0.f,a1=0.f,a2=0.f,a3=0.f;
        #pragma unroll 8
        for (int c = 0; c < CC; ++c) {
            const float* sc = sb + (size_t)c*HWSZ;
            a0 = fmaf(curv[c], sc[o0], a0);
            a1 = fmaf(curv[c], sc[o1], a1);
            a2 = fmaf(curv[c], sc[o2], a2);
            a3 = fmaf(curv[c], sc[o3], a3);
        }
        acc += w00*a0 + w01*a1 + w10*a2 + w11*a3;
    }
    out[(size_t)(b*DD + d)*HWSZ + p] = acc;
}

extern "C" void kernel_launch(void* const* d_in, const int* in_sizes, int n_in,
                              void* d_out, int out_size, void* d_ws, size_t ws_size,
                              hipStream_t stream) {
    const float* cur   = (const float*)d_in[0];
    const float* srcf  = (const float*)d_in[1];
    const float* Emat  = (const float*)d_in[2];
    const float* Kmat  = (const float*)d_in[3];
    const float* invK  = (const float*)d_in[4];
    const float* mn    = (const float*)d_in[5];
    const float* mx    = (const float*)d_in[6];
    float* out = (float*)d_out;

    const size_t srcC_bytes = (size_t)BB*KK*NCH4*HWSZ*8;  // 44 MB
    const size_t curP_bytes = (size_t)BB*NCH4*HWSZ*8;     // 6.3 MB

    if (ws_size >= srcC_bytes + curP_bytes) {
        unsigned* srcC = (unsigned*)d_ws;
        uint2* curP = (uint2*)((char*)d_ws + srcC_bytes);
        int nsrc = BB*KK*NCH4*HWSZ;
        int ncur = BB*NCH4*HWSZ;
        pack_src4<<<dim3((nsrc + 255)/256), dim3(256), 0, stream>>>(srcf, (uint2*)srcC);
        pack_cur4<<<dim3((ncur + 255)/256), dim3(256), 0, stream>>>(cur, curP);
        cv_lds4<<<dim3(BB*(HWSZ/PXT)), dim3(NTHR), 0, stream>>>(curP, srcC, Emat, Kmat, invK, mn, mx, out);
    } else {
        cv_fallback<<<dim3(BB*DD*(HWSZ/256)), dim3(256), 0, stream>>>(cur, srcf, Emat, Kmat, invK, mn, mx, out);
    }
}

// Round 17
// 462.311 us; speedup vs baseline: 1.5430x; 1.0922x over previous
//
#include <hip/hip_runtime.h>
#include <math.h>

#define HH 96
#define WW 128
#define DD 64
#define BB 8
#define KK 7
#define CC 32
#define HWSZ (HH*WW)
#define EPSF 1e-8f
#define NCH 16               // channel-pair chunks (2 f16 ch per u32)
#define NDT 16               // depths per thread
#define PXT 256              // pixels per block tile
#define ROWB 512             // LDS row stride bytes = 128 px * 4B (linear for gload_lds)
#define BIAS 528             // front pad bytes (zeroed; covers iyb=-1 reads)
#define BUFB (BIAS + HH*ROWB + 528)    // 50208 bytes
#define BUFW (BUFB/4)                  // 12552 u32

typedef _Float16 h2 __attribute__((ext_vector_type(2)));

static __device__ __forceinline__ float bf_lo(unsigned u){ return __uint_as_float(u << 16); }
static __device__ __forceinline__ float bf_hi(unsigned u){ return __uint_as_float(u & 0xffff0000u); }
static __device__ __forceinline__ unsigned f2bf(float f){
    unsigned u = __float_as_uint(f);
    return (u + 0x7fffu + ((u >> 16) & 1u)) >> 16;   // RNE
}
static __device__ __forceinline__ unsigned packh2(float a, float b){
    unsigned short ha = __builtin_bit_cast(unsigned short, (_Float16)a);
    unsigned short hb = __builtin_bit_cast(unsigned short, (_Float16)b);
    return ((unsigned)hb << 16) | ha;
}
static __device__ __forceinline__ float dot2h(unsigned a, unsigned b){
#if __has_builtin(__builtin_amdgcn_fdot2)
    return __builtin_amdgcn_fdot2(__builtin_bit_cast(h2, a), __builtin_bit_cast(h2, b), 0.f, false);
#else
    h2 ha = __builtin_bit_cast(h2, a), hb = __builtin_bit_cast(h2, b);
    return (float)ha.x * (float)hb.x + (float)ha.y * (float)hb.y;
#endif
}
static __device__ __forceinline__ void g2lds16(const unsigned* g, unsigned* l){
    __builtin_amdgcn_global_load_lds(
        (const __attribute__((address_space(1))) void*)g,
        (__attribute__((address_space(3))) void*)l, 16, 0, 0);
}

// ---- pack src: (B*K, C, HW) f32 -> (B*K, 16, HW) u32 of 2 f16 ch ----
__global__ __launch_bounds__(256) void pack_src2(const float* __restrict__ in,
                                                 unsigned* __restrict__ outP)
{
    int gid = blockIdx.x * 256 + threadIdx.x;
    int px  = gid % HWSZ;
    int rest = gid / HWSZ;
    int cc  = rest % NCH;
    int v   = rest / NCH;
    if (v >= BB*KK) return;
    const float* ip = in + (size_t)(v*CC + 2*cc)*HWSZ + px;
    outP[(size_t)(v*NCH + cc)*HWSZ + px] = packh2(ip[0], ip[HWSZ]);
}

// ---- pack cur: (B, C, HW) f32 -> (B, 16, HW) u32 of 2 f16 ch ----
__global__ __launch_bounds__(256) void pack_cur2(const float* __restrict__ in,
                                                 unsigned* __restrict__ outP)
{
    int gid = blockIdx.x * 256 + threadIdx.x;
    int px  = gid % HWSZ;
    int rest = gid / HWSZ;
    int cc  = rest % NCH;
    int b   = rest / NCH;
    if (b >= BB) return;
    const float* ip = in + (size_t)(b*CC + 2*cc)*HWSZ + px;
    outP[(size_t)(b*NCH + cc)*HWSZ + px] = packh2(ip[0], ip[HWSZ]);
}

// ---- main: round-9 structure (best known) + setprio around compute ----
__global__ __launch_bounds__(512, 4) void cv_lds(
    const unsigned* __restrict__ curPh,  // (B,16,HW) u32 (2 f16)
    const unsigned* __restrict__ srcC,   // (B,K,16,HW) u32 (2 f16)
    const float* __restrict__ Emat,
    const float* __restrict__ Kmat,
    const float* __restrict__ invK,
    const float* __restrict__ mnp,
    const float* __restrict__ mxp,
    float* __restrict__ out)
{
    __shared__ unsigned sbuf[BUFW];
    __shared__ float sM[KK][12];

    int blk   = blockIdx.x;
    int b     = blk & 7;          // XCD-pinned batch
    int r     = blk >> 3;
    int dhalf = r & 1;
    int tile  = r >> 1;
    int tid   = threadIdx.x;
    int wbase = tid & ~63;        // wave-uniform

    // zero only the front/back pads (weight-0 OOB taps read here; must be finite/0)
    if (tid < BIAS/4)            sbuf[tid] = 0;
    if (tid < (BUFB - BIAS - HH*ROWB)/4) sbuf[BIAS/4 + HH*(ROWB/4) + tid] = 0;

    if (tid < KK) {
        int k = tid;
        const float* Km = Kmat + (size_t)(b*KK + k)*16;
        const float* Em = Emat + (size_t)(b*KK + k)*16;
        float P[3][4];
        #pragma unroll
        for (int i = 0; i < 3; ++i)
            #pragma unroll
            for (int jj = 0; jj < 4; ++jj) {
                float s = 0.f;
                #pragma unroll
                for (int l = 0; l < 4; ++l) s = fmaf(Km[i*4+l], Em[l*4+jj], s);
                P[i][jj] = s;
            }
        const float* iK = invK + (size_t)b*16;
        #pragma unroll
        for (int i = 0; i < 3; ++i) {
            #pragma unroll
            for (int jj = 0; jj < 3; ++jj) {
                float s = 0.f;
                #pragma unroll
                for (int l = 0; l < 3; ++l) s = fmaf(P[i][l], iK[l*4+jj], s);
                sM[k][i*4+jj] = s;
            }
            sM[k][i*4+3] = P[i][3];
        }
    }
    __syncthreads();

    int p     = tile*PXT + (tid & 255);
    int dg    = tid >> 8;                 // 0 or 1
    int dbase = dhalf*32 + dg*NDT;
    float fx = (float)(p & (WW-1)) + 0.5f;
    float fy = (float)(p >> 7) + 0.5f;

    // depths hoisted out of k-loop (16 expf instead of 112)
    float mnb = mnp[b];
    float lmn = logf(mnb);
    float lr  = logf(mxp[b] / mnb);
    float depths[NDT];
    #pragma unroll
    for (int d = 0; d < NDT; ++d)
        depths[d] = expf(fmaf(lr, (float)(dbase + d) * (1.f/63.f), lmn));

    float acc[NDT];
    #pragma unroll
    for (int d = 0; d < NDT; ++d) acc[d] = 0.f;

    unsigned offsP[NDT/2];    // packed dword-offsets, 2 per u32
    unsigned wA[NDT], wB[NDT];
    const char* bp = (const char*)sbuf;

    for (int k = 0; k < KK; ++k) {
        float q0 = fmaf(sM[k][0], fx, fmaf(sM[k][1], fy, sM[k][2]));
        float q1 = fmaf(sM[k][4], fx, fmaf(sM[k][5], fy, sM[k][6]));
        float q2 = fmaf(sM[k][8], fx, fmaf(sM[k][9], fy, sM[k][10]));
        float m3 = sM[k][3], m7 = sM[k][7], m11 = sM[k][11];

        #pragma unroll
        for (int d = 0; d < NDT; ++d) {
            float depth = depths[d];
            float cam0 = fmaf(depth, q0, m3);
            float cam1 = fmaf(depth, q1, m7);
            float zraw = fmaf(depth, q2, m11);
            float z     = zraw + EPSF;
            float scale = (fabsf(zraw) > EPSF) ? (1.f / z) : 1.f;
            float x = cam0 * scale - 0.5f;
            float y = cam1 * scale - 0.5f;
            float x0f = floorf(x), y0f = floorf(y);
            float wx1 = x - x0f,  wy1 = y - y0f;
            float wx0 = 1.f - wx1, wy0 = 1.f - wy1;
            bool vx0 = (x0f >=  0.f) && (x0f <= 127.f);
            bool vx1 = (x0f >= -1.f) && (x0f <= 126.f);
            bool vy0 = (y0f >=  0.f) && (y0f <=  95.f);
            bool vy1 = (y0f >= -1.f) && (y0f <=  94.f);
            float zm = (z > 0.f) ? 1.f : 0.f;
            float w00 = (vx0 && vy0) ? wx0*wy0*zm : 0.f;
            float w01 = (vx1 && vy0) ? wx1*wy0*zm : 0.f;
            float w10 = (vx0 && vy1) ? wx0*wy1*zm : 0.f;
            float w11 = (vx1 && vy1) ? wx1*wy1*zm : 0.f;
            int ixb = (int)fminf(fmaxf(x0f, -1.f), 127.f);
            int iyb = (int)fminf(fmaxf(y0f, -1.f),  95.f);
            unsigned doff = (unsigned)((BIAS/4) + iyb*(ROWB/4) + ixb);
            if ((d & 1) == 0) offsP[d>>1] = doff;
            else              offsP[d>>1] |= (doff << 16);
            wA[d] = (f2bf(w01) << 16) | f2bf(w00);
            wB[d] = (f2bf(w11) << 16) | f2bf(w10);
        }

        const unsigned* kbase = srcC + (size_t)(b*KK + k)*NCH*HWSZ;

        for (int cc = 0; cc < NCH; ++cc) {
            unsigned cp = curPh[(size_t)(b*NCH + cc)*HWSZ + p];   // issue early (L2-hit)
            __syncthreads();   // prior gathers done before overwrite
            // async stage 48KB slice: 6 x global_load_lds dwordx4, zero VGPR/VALU
            {
                const unsigned* gs = kbase + (size_t)cc*HWSZ;
                #pragma unroll
                for (int i = 0; i < 6; ++i) {
                    const unsigned* g = gs + (size_t)(i*512 + tid)*4;
                    unsigned* l = sbuf + (BIAS/4) + (size_t)(i*512 + wbase)*4;
                    g2lds16(g, l);
                }
            }
            __syncthreads();   // drains vmcnt -> LDS ready

            // T5: favor the compute-phase wave over co-resident blocks'
            // staging/address waves (3 independent blocks/CU -> role diversity)
            __builtin_amdgcn_s_setprio(1);
            #pragma unroll
            for (int d = 0; d < NDT; ++d) {
                unsigned doff = (offsP[d>>1] >> ((d & 1)*16)) & 0xffffu;
                const char* tp = bp + doff*4;
                unsigned t00 = *reinterpret_cast<const unsigned*>(tp);
                unsigned t01 = *reinterpret_cast<const unsigned*>(tp + 4);
                unsigned t10 = *reinterpret_cast<const unsigned*>(tp + ROWB);
                unsigned t11 = *reinterpret_cast<const unsigned*>(tp + ROWB + 4);
                float td00 = dot2h(t00, cp);
                float td01 = dot2h(t01, cp);
                float td10 = dot2h(t10, cp);
                float td11 = dot2h(t11, cp);
                unsigned wa = wA[d], wb = wB[d];
                float s = acc[d];
                s = fmaf(bf_lo(wa), td00, s);
                s = fmaf(bf_hi(wa), td01, s);
                s = fmaf(bf_lo(wb), td10, s);
                s = fmaf(bf_hi(wb), td11, s);
                acc[d] = s;
            }
            __builtin_amdgcn_s_setprio(0);
        }
    }

    #pragma unroll
    for (int d = 0; d < NDT; ++d)
        out[(size_t)(b*DD + dbase + d)*HWSZ + p] = acc[d];
}

// ---------- fallback (ws too small): round-1 style, known correct ----------
__global__ __launch_bounds__(256) void cv_fallback(
    const float* __restrict__ cur, const float* __restrict__ src,
    const float* __restrict__ Emat, const float* __restrict__ Kmat,
    const float* __restrict__ invK, const float* __restrict__ mnp,
    const float* __restrict__ mxp, float* __restrict__ out)
{
    int blk  = blockIdx.x;
    int tile = blk % (HWSZ/256);
    int bd   = blk / (HWSZ/256);
    int d    = bd % DD;
    int b    = bd / DD;
    __shared__ float sM[KK][12];
    __shared__ float sDepth;
    if (threadIdx.x < KK) {
        int k = threadIdx.x;
        const float* Km = Kmat + (size_t)(b*KK + k)*16;
        const float* Em = Emat + (size_t)(b*KK + k)*16;
        float P[3][4];
        #pragma unroll
        for (int i = 0; i < 3; ++i)
            #pragma unroll
            for (int jj = 0; jj < 4; ++jj) {
                float s = 0.f;
                #pragma unroll
                for (int l = 0; l < 4; ++l) s = fmaf(Km[i*4+l], Em[l*4+jj], s);
                P[i][jj] = s;
            }
        const float* iK = invK + (size_t)b*16;
        #pragma unroll
        for (int i = 0; i < 3; ++i) {
            #pragma unroll
            for (int jj = 0; jj < 3; ++jj) {
                float s = 0.f;
                #pragma unroll
                for (int l = 0; l < 3; ++l) s = fmaf(P[i][l], iK[l*4+jj], s);
                sM[k][i*4+jj] = s;
            }
            sM[k][i*4+3] = P[i][3];
        }
    }
    if (threadIdx.x == KK) {
        float mnb = mnp[b], mxb = mxp[b];
        sDepth = expf(logf(mnb) + logf(mxb/mnb) * ((float)d * (1.f/63.f)));
    }
    __syncthreads();
    int p  = tile*256 + threadIdx.x;
    float fx = (float)(p & (WW-1)) + 0.5f;
    float fy = (float)(p >> 7) + 0.5f;
    float depth = sDepth;
    float curv[CC];
    const float* curp = cur + (size_t)b*CC*HWSZ + p;
    #pragma unroll
    for (int c = 0; c < CC; ++c) curv[c] = curp[(size_t)c*HWSZ];
    float acc = 0.f;
    for (int k = 0; k < KK; ++k) {
        float q0 = fmaf(sM[k][0], fx, fmaf(sM[k][1], fy, sM[k][2]));
        float q1 = fmaf(sM[k][4], fx, fmaf(sM[k][5], fy, sM[k][6]));
        float q2 = fmaf(sM[k][8], fx, fmaf(sM[k][9], fy, sM[k][10]));
        float cam0 = fmaf(depth, q0, sM[k][3]);
        float cam1 = fmaf(depth, q1, sM[k][7]);
        float zraw = fmaf(depth, q2, sM[k][11]);
        float z     = zraw + EPSF;
        float scale = (fabsf(zraw) > EPSF) ? (1.f / z) : 1.f;
        float x = cam0 * scale - 0.5f;
        float y = cam1 * scale - 0.5f;
        float x0f = floorf(x), y0f = floorf(y);
        float wx1 = x - x0f,  wy1 = y - y0f;
        float wx0 = 1.f - wx1, wy0 = 1.f - wy1;
        bool vx0 = (x0f >= 0.f)   && (x0f <= 127.f);
        bool vx1 = (x0f >= -1.f)  && (x0f <= 126.f);
        bool vy0 = (y0f >= 0.f)   && (y0f <= 95.f);
        bool vy1 = (y0f >= -1.f)  && (y0f <= 94.f);
        float zm = (z > 0.f) ? 1.f : 0.f;
        float w00 = (vx0 && vy0) ? wx0*wy0*zm : 0.f;
        float w01 = (vx1 && vy0) ? wx1*wy0*zm : 0.f;
        float w10 = (vx0 && vy1) ? wx0*wy1*zm : 0.f;
        float w11 = (vx1 && vy1) ? wx1*wy1*zm : 0.f;
        int ix0 = (int)fminf(fmaxf(x0f,       0.f), 127.f);
        int ix1 = (int)fminf(fmaxf(x0f + 1.f, 0.f), 127.f);
        int iy0 = (int)fminf(fmaxf(y0f,       0.f), 95.f);
        int iy1 = (int)fminf(fmaxf(y0f + 1.f, 0.f), 95.f);
        const float* sb = src + (size_t)(b*KK + k)*CC*HWSZ;
        int o0 = iy0*WW+ix0, o1 = iy0*WW+ix1, o2 = iy1*WW+ix0, o3 = iy1*WW+ix1;
        float a0=0.f,a1=0.f,a2=0.f,a3=0.f;
        #pragma unroll 8
        for (int c = 0; c < CC; ++c) {
            const float* sc = sb + (size_t)c*HWSZ;
            a0 = fmaf(curv[c], sc[o0], a0);
            a1 = fmaf(curv[c], sc[o1], a1);
            a2 = fmaf(curv[c], sc[o2], a2);
            a3 = fmaf(curv[c], sc[o3], a3);
        }
        acc += w00*a0 + w01*a1 + w10*a2 + w11*a3;
    }
    out[(size_t)(b*DD + d)*HWSZ + p] = acc;
}

extern "C" void kernel_launch(void* const* d_in, const int* in_sizes, int n_in,
                              void* d_out, int out_size, void* d_ws, size_t ws_size,
                              hipStream_t stream) {
    const float* cur   = (const float*)d_in[0];
    const float* srcf  = (const float*)d_in[1];
    const float* Emat  = (const float*)d_in[2];
    const float* Kmat  = (const float*)d_in[3];
    const float* invK  = (const float*)d_in[4];
    const float* mn    = (const float*)d_in[5];
    const float* mx    = (const float*)d_in[6];
    float* out = (float*)d_out;

    const size_t srcC_bytes = (size_t)BB*KK*NCH*HWSZ*4;   // 44 MB
    const size_t curP_bytes = (size_t)BB*NCH*HWSZ*4;      // 6.3 MB

    if (ws_size >= srcC_bytes + curP_bytes) {
        unsigned* srcC = (unsigned*)d_ws;
        unsigned* curP = (unsigned*)((char*)d_ws + srcC_bytes);
        int nsrc = BB*KK*NCH*HWSZ;
        int ncur = BB*NCH*HWSZ;
        pack_src2<<<dim3((nsrc + 255)/256), dim3(256), 0, stream>>>(srcf, srcC);
        pack_cur2<<<dim3((ncur + 255)/256), dim3(256), 0, stream>>>(cur, curP);
        cv_lds<<<dim3(BB*(HWSZ/PXT)*2), dim3(512), 0, stream>>>(curP, srcC, Emat, Kmat, invK, mn, mx, out);
    } else {
        cv_fallback<<<dim3(BB*DD*(HWSZ/256)), dim3(256), 0, stream>>>(cur, srcf, Emat, Kmat, invK, mn, mx, out);
    }
}